// Round 1
// baseline (847.246 us; speedup 1.0000x reference)
//
#include <hip/hip_runtime.h>

#define N_BATCH 8
#define I_DIM   32768
#define T_DIM   300
#define O1      410
#define O2      10
#define KLEN    100
#define NSEG    4
#define SEG_I   (I_DIM / NSEG)   // 8192
#define SEGCAP  448               // binomial(8192,0.03): mean 246, +13 sigma
#define GT      448               // gather block threads (7 waves)

// ---------------- w1 transpose: (410, 32768) -> (32768, 410) ----------------
__global__ void transpose_w1_k(const float* __restrict__ w1, float* __restrict__ w1t) {
    __shared__ float tile[64][65];
    int i0 = blockIdx.x * 64;
    int o0 = blockIdx.y * 64;
    int tx = threadIdx.x & 63;
    int ty = threadIdx.x >> 6;  // 0..3
#pragma unroll
    for (int r = 0; r < 64; r += 4) {
        int o = o0 + r + ty;
        tile[r + ty][tx] = (o < O1) ? w1[(size_t)o * I_DIM + i0 + tx] : 0.0f;
    }
    __syncthreads();
#pragma unroll
    for (int r = 0; r < 64; r += 4) {
        int i = i0 + r + ty;
        int o = o0 + tx;
        if (o < O1) w1t[(size_t)i * O1 + o] = tile[tx][r + ty];
    }
}

// -------- build active-index lists per (n,t), deterministic ascending-i -----
// grid: (N_BATCH, ceil(T/16), NSEG), block: 64 (one wave)
__global__ void build_lists_k(const float* __restrict__ x, int* __restrict__ lists,
                              int* __restrict__ counts) {
    int n    = blockIdx.x;
    int t0   = blockIdx.y * 16;
    int seg  = blockIdx.z;
    int lane = threadIdx.x;

    int cnt[16];
#pragma unroll
    for (int tt = 0; tt < 16; tt++) cnt[tt] = 0;

    unsigned long long below = (1ULL << lane) - 1ULL;
    int ibase = seg * SEG_I;

    for (int ii = 0; ii < SEG_I; ii += 64) {
        int i = ibase + ii + lane;
        const float* row = x + ((size_t)(n * I_DIM + i)) * T_DIM + t0;
        float4 q[4];
#pragma unroll
        for (int k = 0; k < 4; k++) {
            if (t0 + 4 * k < T_DIM) q[k] = *reinterpret_cast<const float4*>(row + 4 * k);
            else                    q[k] = make_float4(0.f, 0.f, 0.f, 0.f);
        }
        float vals[16];
#pragma unroll
        for (int k = 0; k < 4; k++) {
            vals[4 * k + 0] = q[k].x; vals[4 * k + 1] = q[k].y;
            vals[4 * k + 2] = q[k].z; vals[4 * k + 3] = q[k].w;
        }
#pragma unroll
        for (int tt = 0; tt < 16; tt++) {
            if (t0 + tt < T_DIM) {
                bool act = (vals[tt] != 0.0f);
                unsigned long long m = __ballot(act);
                if (act) {
                    int pos = cnt[tt] + (int)__popcll(m & below);
                    if (pos < SEGCAP)
                        lists[(size_t)((n * T_DIM + t0 + tt) * NSEG + seg) * SEGCAP + pos] = i;
                }
                cnt[tt] += (int)__popcll(m);
            }
        }
    }
    if (lane == 0) {
#pragma unroll
        for (int tt = 0; tt < 16; tt++) {
            if (t0 + tt < T_DIM) {
                int c = cnt[tt];
                if (c > SEGCAP) c = SEGCAP;
                counts[(n * T_DIM + t0 + tt) * NSEG + seg] = c;
            }
        }
    }
}

// -------- sparse gather-GEMM: u_pre1[n,o,t] = sum_{i active} w1t[i][o] -------
// grid: N*T blocks, block: GT threads (thread tid = output o)
__global__ __launch_bounds__(GT) void gather_gemm_k(const float* __restrict__ w1t,
                                                    const int* __restrict__ counts,
                                                    const int* __restrict__ lists,
                                                    float* __restrict__ up1) {
    int nt  = blockIdx.x;  // n*T + t
    int tid = threadIdx.x;
    __shared__ int s_idx[NSEG * SEGCAP];
    __shared__ int s_off[NSEG + 1];

    if (tid == 0) {
        int off = 0;
        for (int k = 0; k < NSEG; k++) { s_off[k] = off; off += counts[nt * NSEG + k]; }
        s_off[NSEG] = off;
    }
    __syncthreads();
    for (int k = 0; k < NSEG; k++) {
        int base = s_off[k];
        int c    = s_off[k + 1] - base;
        const int* src = lists + (size_t)(nt * NSEG + k) * SEGCAP;
        for (int j = tid; j < c; j += GT) s_idx[base + j] = src[j];
    }
    __syncthreads();

    int total = s_off[NSEG];
    if (tid < O1) {
        float a0 = 0, a1 = 0, a2 = 0, a3 = 0, a4 = 0, a5 = 0, a6 = 0, a7 = 0;
        int j = 0;
        for (; j + 8 <= total; j += 8) {
            a0 += w1t[(size_t)s_idx[j + 0] * O1 + tid];
            a1 += w1t[(size_t)s_idx[j + 1] * O1 + tid];
            a2 += w1t[(size_t)s_idx[j + 2] * O1 + tid];
            a3 += w1t[(size_t)s_idx[j + 3] * O1 + tid];
            a4 += w1t[(size_t)s_idx[j + 4] * O1 + tid];
            a5 += w1t[(size_t)s_idx[j + 5] * O1 + tid];
            a6 += w1t[(size_t)s_idx[j + 6] * O1 + tid];
            a7 += w1t[(size_t)s_idx[j + 7] * O1 + tid];
        }
        for (; j < total; j++) a0 += w1t[(size_t)s_idx[j] * O1 + tid];
        float acc = ((a0 + a1) + (a2 + a3)) + ((a4 + a5) + (a6 + a7));
        int n = nt / T_DIM, t = nt - n * T_DIM;
        up1[((size_t)(n * O1 + tid)) * T_DIM + t] = acc;
    }
}

// ------------- causal FIR with truncated SRM alpha kernel (100 taps) --------
// grid: nrows blocks (row = 300 contiguous floats), block: 320 threads
__global__ void psp_k(const float* __restrict__ z, float* __restrict__ u) {
    __shared__ float row[T_DIM];
    __shared__ float kern[KLEN];
    int r = blockIdx.x;
    int t = threadIdx.x;
    if (t < KLEN) {
        float tm = (float)t;
        float a  = tm / 10.0f;            // t/tauSr, mimic f32 ref math
        kern[t]  = a * expf(1.0f - a);
    }
    if (t < T_DIM) row[t] = z[(size_t)r * T_DIM + t];
    __syncthreads();
    if (t < T_DIM) {
        float acc = 0.0f;
        int mmax = t < (KLEN - 1) ? t : (KLEN - 1);
        for (int m = 0; m <= mmax; m++) acc += kern[m] * row[t - m];
        u[(size_t)r * T_DIM + t] = acc;
    }
}

// ---------- sequential threshold + alpha refractory (2nd-order IIR) ---------
__global__ void spike_k(const float* __restrict__ u, float* __restrict__ s, int nrows) {
    int r = blockIdx.x * blockDim.x + threadIdx.x;
    if (r >= nrows) return;
    const float A = 0.36787944117144233f;   // exp(-1)
    const float K = -54.365636569180904f;   // -2*10*e
    const float* ur = u + (size_t)r * T_DIM;
    float*       sr = s + (size_t)r * T_DIM;
    float p = 0.0f, y = 0.0f;
    for (int t = 0; t < T_DIM; t++) {
        y = A * (y + K * p);
        float sp = (ur[t] + y >= 10.0f) ? 1.0f : 0.0f;
        p = A * p + sp;
        sr[t] = sp;
    }
}

// ---------------- dense tiny GEMM2: (8,410,300) x (10,410) ------------------
__global__ void gemm2_k(const float* __restrict__ s1, const float* __restrict__ w2,
                        float* __restrict__ up2) {
    int id = blockIdx.x * 256 + threadIdx.x;
    if (id >= N_BATCH * O2 * T_DIM) return;
    int t  = id % T_DIM;
    int o2 = (id / T_DIM) % O2;
    int n  = id / (T_DIM * O2);
    const float* s1n = s1 + (size_t)n * O1 * T_DIM + t;
    const float* w2r = w2 + o2 * O1;
    float a0 = 0, a1 = 0;
    for (int o = 0; o + 2 <= O1; o += 2) {
        a0 += w2r[o]     * s1n[(size_t)o * T_DIM];
        a1 += w2r[o + 1] * s1n[(size_t)(o + 1) * T_DIM];
    }
    up2[id] = a0 + a1;   // layout (n,o2,t): rows of 300, matches psp_k/spike_k
}

extern "C" void kernel_launch(void* const* d_in, const int* in_sizes, int n_in,
                              void* d_out, int out_size, void* d_ws, size_t ws_size,
                              hipStream_t stream) {
    const float* x  = (const float*)d_in[0];
    const float* w1 = (const float*)d_in[1];
    const float* w2 = (const float*)d_in[2];
    float* out = (float*)d_out;

    char* ws = (char*)d_ws;
    float* w1t   = (float*)ws;  ws += (size_t)I_DIM * O1 * 4;                      // 53.7 MB
    int*   counts = (int*)ws;   ws += (size_t)N_BATCH * T_DIM * NSEG * 4;          // 38 KB
    int*   lists  = (int*)ws;   ws += (size_t)N_BATCH * T_DIM * NSEG * SEGCAP * 4; // 17.2 MB
    float* up1   = (float*)ws;  ws += (size_t)N_BATCH * O1 * T_DIM * 4;            // 3.9 MB
    float* u1    = (float*)ws;  ws += (size_t)N_BATCH * O1 * T_DIM * 4;
    float* s1    = (float*)ws;  ws += (size_t)N_BATCH * O1 * T_DIM * 4;
    float* up2   = (float*)ws;  ws += (size_t)N_BATCH * O2 * T_DIM * 4;
    float* u2    = (float*)ws;

    transpose_w1_k<<<dim3(I_DIM / 64, (O1 + 63) / 64), 256, 0, stream>>>(w1, w1t);
    build_lists_k<<<dim3(N_BATCH, (T_DIM + 15) / 16, NSEG), 64, 0, stream>>>(x, lists, counts);
    gather_gemm_k<<<N_BATCH * T_DIM, GT, 0, stream>>>(w1t, counts, lists, up1);
    psp_k<<<N_BATCH * O1, 320, 0, stream>>>(up1, u1);
    spike_k<<<(N_BATCH * O1 + 255) / 256, 256, 0, stream>>>(u1, s1, N_BATCH * O1);
    gemm2_k<<<(N_BATCH * O2 * T_DIM + 255) / 256, 256, 0, stream>>>(s1, w2, up2);
    psp_k<<<N_BATCH * O2, 320, 0, stream>>>(up2, u2);
    spike_k<<<1, 128, 0, stream>>>(u2, out, N_BATCH * O2);
}

// Round 2
// 427.995 us; speedup vs baseline: 1.9796x; 1.9796x over previous
//
#include <hip/hip_runtime.h>

#define N_BATCH 8
#define I_DIM   32768
#define T_DIM   300
#define O1      410
#define O1P     416               // padded to 104 float4
#define O1Q     104               // float4s per row
#define O2      10
#define KLEN    100
#define NSEG    16                // chunks of i, == L2 pin chunks
#define SEG_I   (I_DIM / NSEG)    // 2048
#define SEGCAP  128               // binomial(2048,0.03): mean 61, +8.6 sigma
#define NT      (N_BATCH * T_DIM) // 2400
#define GRP     4                 // nt per gather block
#define NTG     (NT / GRP)        // 600

// ---------------- w1 transpose: (410, 32768) -> (32768, 416) zero-padded ----
__global__ void transpose_w1_k(const float* __restrict__ w1, float* __restrict__ w1t) {
    __shared__ float tile[64][65];
    int i0 = blockIdx.x * 64;
    int o0 = blockIdx.y * 64;
    int tx = threadIdx.x & 63;
    int ty = threadIdx.x >> 6;  // 0..3
#pragma unroll
    for (int r = 0; r < 64; r += 4) {
        int o = o0 + r + ty;
        tile[r + ty][tx] = (o < O1) ? w1[(size_t)o * I_DIM + i0 + tx] : 0.0f;
    }
    __syncthreads();
#pragma unroll
    for (int r = 0; r < 64; r += 4) {
        int i = i0 + r + ty;
        int o = o0 + tx;
        if (o < O1P) w1t[(size_t)i * O1P + o] = (o < O1) ? tile[tx][r + ty] : 0.0f;
    }
}

// -------- build active-index lists per (n,t,seg), deterministic ascending-i -
// grid: (N_BATCH, ceil(T/16), NSEG), block: 64 (one wave)
__global__ void build_lists_k(const float* __restrict__ x, int* __restrict__ lists,
                              int* __restrict__ counts) {
    int n    = blockIdx.x;
    int t0   = blockIdx.y * 16;
    int seg  = blockIdx.z;
    int lane = threadIdx.x;

    int cnt[16];
#pragma unroll
    for (int tt = 0; tt < 16; tt++) cnt[tt] = 0;

    unsigned long long below = (1ULL << lane) - 1ULL;
    int ibase = seg * SEG_I;

    for (int ii = 0; ii < SEG_I; ii += 64) {
        int i = ibase + ii + lane;
        const float* row = x + ((size_t)(n * I_DIM + i)) * T_DIM + t0;
        float4 q[4];
#pragma unroll
        for (int k = 0; k < 4; k++) {
            if (t0 + 4 * k < T_DIM) q[k] = *reinterpret_cast<const float4*>(row + 4 * k);
            else                    q[k] = make_float4(0.f, 0.f, 0.f, 0.f);
        }
        float vals[16];
#pragma unroll
        for (int k = 0; k < 4; k++) {
            vals[4 * k + 0] = q[k].x; vals[4 * k + 1] = q[k].y;
            vals[4 * k + 2] = q[k].z; vals[4 * k + 3] = q[k].w;
        }
#pragma unroll
        for (int tt = 0; tt < 16; tt++) {
            if (t0 + tt < T_DIM) {
                bool act = (vals[tt] != 0.0f);
                unsigned long long m = __ballot(act);
                if (act) {
                    int pos = cnt[tt] + (int)__popcll(m & below);
                    if (pos < SEGCAP)
                        lists[(size_t)((n * T_DIM + t0 + tt) * NSEG + seg) * SEGCAP + pos] = i;
                }
                cnt[tt] += (int)__popcll(m);
            }
        }
    }
    if (lane == 0) {
#pragma unroll
        for (int tt = 0; tt < 16; tt++) {
            if (t0 + tt < T_DIM) {
                int c = cnt[tt];
                if (c > SEGCAP) c = SEGCAP;
                counts[(n * T_DIM + t0 + tt) * NSEG + seg] = c;
            }
        }
    }
}

__device__ __forceinline__ void add4(float4& a, const float4 b) {
    a.x += b.x; a.y += b.y; a.z += b.z; a.w += b.w;
}

// ------ chunk-pinned sparse gather: partial[nt][chunk][o] over chunk's rows -
// 1-D grid of 2*NTG*8 blocks; b -> (phase, ntg, k), chunk = phase*8+k.
// b%8==k pins chunk k (then k+8) to XCD k so its 3.4 MB w1t slice stays in L2.
__global__ __launch_bounds__(512) void gather_partial_k(
        const float4* __restrict__ w1t4, const int* __restrict__ counts,
        const int* __restrict__ lists, float4* __restrict__ partial4) {
    int b     = blockIdx.x;
    int phase = b / (NTG * 8);
    int rem   = b - phase * (NTG * 8);
    int ntg   = rem >> 3;
    int k     = rem & 7;
    int chunk = phase * 8 + k;
    int nt0   = ntg * GRP;
    int tid   = threadIdx.x;

    __shared__ int s_idx[GRP][SEGCAP];
    __shared__ int s_cnt[GRP];

    if (tid < GRP) s_cnt[tid] = counts[(nt0 + tid) * NSEG + chunk];
    __syncthreads();
    for (int j = tid; j < GRP * SEGCAP; j += 512) {
        int g = j >> 7, jj = j & (SEGCAP - 1);
        if (jj < s_cnt[g]) s_idx[g][jj] = lists[(size_t)((nt0 + g) * NSEG + chunk) * SEGCAP + jj];
    }
    __syncthreads();

    int g  = tid >> 7;        // 0..3
    int oq = tid & 127;       // 0..127, active < 104
    if (oq < O1Q) {
        const float4* wb = w1t4 + oq;
        int c = s_cnt[g];
        float4 z4 = make_float4(0.f, 0.f, 0.f, 0.f);
        float4 a0 = z4, a1 = z4, a2 = z4, a3 = z4;
        int j = 0;
        for (; j + 4 <= c; j += 4) {
            add4(a0, wb[(size_t)s_idx[g][j + 0] * O1Q]);
            add4(a1, wb[(size_t)s_idx[g][j + 1] * O1Q]);
            add4(a2, wb[(size_t)s_idx[g][j + 2] * O1Q]);
            add4(a3, wb[(size_t)s_idx[g][j + 3] * O1Q]);
        }
        for (; j < c; j++) add4(a0, wb[(size_t)s_idx[g][j] * O1Q]);
        add4(a0, a1); add4(a2, a3); add4(a0, a2);
        partial4[((size_t)(nt0 + g) * NSEG + chunk) * O1Q + oq] = a0;
    }
}

// ---- reduce 16 chunk partials -> up1[n][o][t], fixed ascending-chunk order -
__global__ void reduce_k(const float* __restrict__ partial, float* __restrict__ up1) {
    int id = blockIdx.x * 256 + threadIdx.x;
    if (id >= NT * O1P) return;
    int nt = id / O1P;
    int o  = id - nt * O1P;
    float s = 0.0f;
    const float* p = partial + (size_t)nt * NSEG * O1P + o;
#pragma unroll
    for (int c = 0; c < NSEG; c++) s += p[c * O1P];
    if (o < O1) {
        int n = nt / T_DIM, t = nt - n * T_DIM;
        up1[((size_t)(n * O1 + o)) * T_DIM + t] = s;
    }
}

// ---- fused: causal 100-tap SRM FIR + sequential threshold/refractory scan --
// grid: nrows blocks (row = 300 contiguous floats), block: 320 threads
__global__ void psp_spike_k(const float* __restrict__ z, float* __restrict__ s) {
    __shared__ float row[T_DIM];
    __shared__ float u[T_DIM];
    __shared__ float sp[T_DIM];
    __shared__ float kern[KLEN];
    int r = blockIdx.x;
    int t = threadIdx.x;
    if (t < KLEN) {
        float a = (float)t / 10.0f;       // t/tauSr, f32 like reference
        kern[t] = a * expf(1.0f - a);
    }
    if (t < T_DIM) row[t] = z[(size_t)r * T_DIM + t];
    __syncthreads();
    if (t < T_DIM) {
        float acc = 0.0f;
        int mmax = t < (KLEN - 1) ? t : (KLEN - 1);
        for (int m = 0; m <= mmax; m++) acc += kern[m] * row[t - m];
        u[t] = acc;
    }
    __syncthreads();
    if (t == 0) {
        const float A = 0.36787944117144233f;   // exp(-1)
        const float K = -54.365636569180904f;   // -2*10*e
        float p = 0.0f, y = 0.0f;
        for (int t0 = 0; t0 < T_DIM; t0 += 10) {
            float uv[10];
#pragma unroll
            for (int q = 0; q < 10; q++) uv[q] = u[t0 + q];   // batch LDS reads
#pragma unroll
            for (int q = 0; q < 10; q++) {
                y = A * (y + K * p);
                float spk = (uv[q] + y >= 10.0f) ? 1.0f : 0.0f;
                p = A * p + spk;
                sp[t0 + q] = spk;
            }
        }
    }
    __syncthreads();
    if (t < T_DIM) s[(size_t)r * T_DIM + t] = sp[t];
}

// ---------------- dense tiny GEMM2: (8,410,300) x (10,410) ------------------
__global__ void gemm2_k(const float* __restrict__ s1, const float* __restrict__ w2,
                        float* __restrict__ up2) {
    int id = blockIdx.x * 256 + threadIdx.x;
    if (id >= N_BATCH * O2 * T_DIM) return;
    int t  = id % T_DIM;
    int o2 = (id / T_DIM) % O2;
    int n  = id / (T_DIM * O2);
    const float* s1n = s1 + (size_t)n * O1 * T_DIM + t;
    const float* w2r = w2 + o2 * O1;
    float a0 = 0, a1 = 0;
    for (int o = 0; o + 2 <= O1; o += 2) {
        a0 += w2r[o]     * s1n[(size_t)o * T_DIM];
        a1 += w2r[o + 1] * s1n[(size_t)(o + 1) * T_DIM];
    }
    up2[id] = a0 + a1;   // layout (n,o2,t)
}

extern "C" void kernel_launch(void* const* d_in, const int* in_sizes, int n_in,
                              void* d_out, int out_size, void* d_ws, size_t ws_size,
                              hipStream_t stream) {
    const float* x  = (const float*)d_in[0];
    const float* w1 = (const float*)d_in[1];
    const float* w2 = (const float*)d_in[2];
    float* out = (float*)d_out;

    char* ws = (char*)d_ws;
    float* w1t    = (float*)ws;  ws += (size_t)I_DIM * O1P * 4;            // 54.5 MB
    int*   counts = (int*)ws;    ws += (size_t)NT * NSEG * 4;              // 154 KB
    int*   lists  = (int*)ws;    ws += (size_t)NT * NSEG * SEGCAP * 4;     // 19.7 MB
    float* partial= (float*)ws;  ws += (size_t)NT * NSEG * O1P * 4;        // 63.9 MB
    float* up1    = (float*)ws;  ws += (size_t)N_BATCH * O1 * T_DIM * 4;   // 3.9 MB
    float* s1     = (float*)ws;  ws += (size_t)N_BATCH * O1 * T_DIM * 4;   // 3.9 MB
    float* up2    = (float*)ws;                                            // 96 KB

    transpose_w1_k<<<dim3(I_DIM / 64, (O1P + 63) / 64), 256, 0, stream>>>(w1, w1t);
    build_lists_k<<<dim3(N_BATCH, (T_DIM + 15) / 16, NSEG), 64, 0, stream>>>(x, lists, counts);
    gather_partial_k<<<2 * NTG * 8, 512, 0, stream>>>((const float4*)w1t, counts, lists,
                                                      (float4*)partial);
    reduce_k<<<(NT * O1P + 255) / 256, 256, 0, stream>>>(partial, up1);
    psp_spike_k<<<N_BATCH * O1, 320, 0, stream>>>(up1, s1);
    gemm2_k<<<(N_BATCH * O2 * T_DIM + 255) / 256, 256, 0, stream>>>(s1, w2, up2);
    psp_spike_k<<<N_BATCH * O2, 320, 0, stream>>>(up2, out);
}